// Round 1
// baseline (673.063 us; speedup 1.0000x reference)
//
#include <hip/hip_runtime.h>
#include <math.h>

// Problem constants from the reference: B=8, O=8, S=32, C=64, H=32, W=32, HID=C
#define Bc 8
#define Oc 8
#define Sc 32
#define Cc 64
#define HWc 1024            // H*W
#define NBLK (Bc*Oc*Sc)     // 2048 samples, one block each

// One block = one (b,o,s) sample.
// Phase 1: 4 waves x 16 channels each; per channel, wave-wide reduce of 1024
//          contiguous floats (mean + max) via float4 loads + shfl_xor.
// Phase 2: threads 0..63 run the 64->64->64 MLP (mean path + max path),
//          sigmoid, store 64 outputs.
__global__ __launch_bounds__(256) void ca_fused(const float* __restrict__ x,
                                                const float* __restrict__ w1,
                                                const float* __restrict__ w2,
                                                float* __restrict__ out) {
    __shared__ float s_mean[Cc];
    __shared__ float s_max[Cc];
    __shared__ float s_hm[Cc];
    __shared__ float s_hx[Cc];

    const int blk  = blockIdx.x;            // (b*O + o)*S + s
    const int o    = (blk / Sc) % Oc;       // group index
    const int tid  = threadIdx.x;
    const int wave = tid >> 6;
    const int lane = tid & 63;

    const float* xb = x + (size_t)blk * (Cc * HWc);

    // ---- Phase 1: pooling ----
    #pragma unroll 4
    for (int ci = 0; ci < 16; ++ci) {
        const int c = wave * 16 + ci;
        const float4* p = (const float4*)(xb + (size_t)c * HWc);
        // 1024 floats = 256 float4; lane i takes float4 i, i+64, i+128, i+192
        float4 v0 = p[lane];
        float4 v1 = p[lane + 64];
        float4 v2 = p[lane + 128];
        float4 v3 = p[lane + 192];

        float sum = (v0.x + v0.y) + (v0.z + v0.w)
                  + (v1.x + v1.y) + (v1.z + v1.w)
                  + (v2.x + v2.y) + (v2.z + v2.w)
                  + (v3.x + v3.y) + (v3.z + v3.w);
        float mx  = fmaxf(fmaxf(fmaxf(v0.x, v0.y), fmaxf(v0.z, v0.w)),
                    fmaxf(fmaxf(fmaxf(v1.x, v1.y), fmaxf(v1.z, v1.w)),
                    fmaxf(fmaxf(fmaxf(v2.x, v2.y), fmaxf(v2.z, v2.w)),
                          fmaxf(fmaxf(v3.x, v3.y), fmaxf(v3.z, v3.w)))));

        // wave-64 butterfly reduction
        #pragma unroll
        for (int m = 32; m >= 1; m >>= 1) {
            sum += __shfl_xor(sum, m, 64);
            mx   = fmaxf(mx, __shfl_xor(mx, m, 64));
        }
        if (lane == 0) {
            s_mean[c] = sum * (1.0f / 1024.0f);
            s_max[c]  = mx;
        }
    }
    __syncthreads();

    // ---- Phase 2: grouped MLP on threads 0..63 ----
    if (tid < Cc) {
        // FC1: h[tid] = relu(sum_c p[c] * w1[o][tid][c])
        const float* w1o = w1 + ((size_t)o * Cc + tid) * Cc;
        float am = 0.f, ax = 0.f;
        #pragma unroll
        for (int c2 = 0; c2 < Cc; ++c2) {
            const float w = w1o[c2];
            am = fmaf(s_mean[c2], w, am);
            ax = fmaf(s_max[c2],  w, ax);
        }
        s_hm[tid] = fmaxf(am, 0.f);
        s_hx[tid] = fmaxf(ax, 0.f);
    }
    __syncthreads();

    if (tid < Cc) {
        // FC2: out[tid] = sigmoid(sum_h hm[h]*w2[o][tid][h] + sum_h hx[h]*w2[o][tid][h])
        const float* w2o = w2 + ((size_t)o * Cc + tid) * Cc;
        float am = 0.f, ax = 0.f;
        #pragma unroll
        for (int h = 0; h < Cc; ++h) {
            const float w = w2o[h];
            am = fmaf(s_hm[h], w, am);
            ax = fmaf(s_hx[h], w, ax);
        }
        const float z = am + ax;
        out[(size_t)blk * Cc + tid] = 1.0f / (1.0f + __expf(-z));
    }
}

extern "C" void kernel_launch(void* const* d_in, const int* in_sizes, int n_in,
                              void* d_out, int out_size, void* d_ws, size_t ws_size,
                              hipStream_t stream) {
    const float* x  = (const float*)d_in[0];
    const float* w1 = (const float*)d_in[1];
    const float* w2 = (const float*)d_in[2];
    float* out = (float*)d_out;

    ca_fused<<<NBLK, 256, 0, stream>>>(x, w1, w2, out);
}

// Round 2
// 649.465 us; speedup vs baseline: 1.0363x; 1.0363x over previous
//
#include <hip/hip_runtime.h>
#include <math.h>

// B=8, O=8, S=32, C=64, H=32, W=32, HID=C
#define Bc 8
#define Oc 8
#define Sc 32
#define Cc 64
#define HWc 1024
#define NBLK (Bc*Oc*Sc)     // 2048 blocks, one (b,o,s) sample each

typedef float f4 __attribute__((ext_vector_type(4)));

static __device__ __forceinline__ float hsum(f4 a) { return (a.x + a.y) + (a.z + a.w); }
static __device__ __forceinline__ float hmax(f4 a) { return fmaxf(fmaxf(a.x, a.y), fmaxf(a.z, a.w)); }
static __device__ __forceinline__ f4 vmax4(f4 a, f4 b) {
    f4 r; r.x = fmaxf(a.x, b.x); r.y = fmaxf(a.y, b.y);
    r.z = fmaxf(a.z, b.z); r.w = fmaxf(a.w, b.w); return r;
}

// Phase 1: 4 waves x 16 channels; groups of 2 channels (8 float4 live -> low
//          VGPR, target 8 waves/SIMD). Nontemporal loads: x is streamed once.
// Phase 2: wave0 = mean path, wave1 = max path, combined at the end.
__global__ __launch_bounds__(256) void ca_fused(const float* __restrict__ x,
                                                const float* __restrict__ w1,
                                                const float* __restrict__ w2,
                                                float* __restrict__ out) {
    __shared__ float s_mean[Cc];
    __shared__ float s_max[Cc];
    __shared__ float s_hm[Cc];
    __shared__ float s_hx[Cc];
    __shared__ float s_ax[Cc];

    const int blk  = blockIdx.x;            // (b*O + o)*S + s
    const int o    = (blk / Sc) % Oc;       // group index
    const int tid  = threadIdx.x;
    const int wave = tid >> 6;
    const int lane = tid & 63;

    const f4* xb = (const f4*)(x + (size_t)blk * (Cc * HWc)) + lane;

    // ---- Phase 1: pooling (mean + max over 1024 floats per channel) ----
    #pragma unroll
    for (int g = 0; g < 8; ++g) {
        const int c0 = wave * 16 + g * 2;       // 2 channels per group
        const f4* p0 = xb + (size_t)c0 * 256;   // 256 f4 per channel
        const f4* p1 = p0 + 256;

        f4 a0 = __builtin_nontemporal_load(p0);
        f4 a1 = __builtin_nontemporal_load(p0 + 64);
        f4 a2 = __builtin_nontemporal_load(p0 + 128);
        f4 a3 = __builtin_nontemporal_load(p0 + 192);
        f4 b0 = __builtin_nontemporal_load(p1);
        f4 b1 = __builtin_nontemporal_load(p1 + 64);
        f4 b2 = __builtin_nontemporal_load(p1 + 128);
        f4 b3 = __builtin_nontemporal_load(p1 + 192);

        f4 sa = (a0 + a1) + (a2 + a3);
        f4 ma = vmax4(vmax4(a0, a1), vmax4(a2, a3));
        f4 sb = (b0 + b1) + (b2 + b3);
        f4 mb = vmax4(vmax4(b0, b1), vmax4(b2, b3));

        float s0 = hsum(sa), m0 = hmax(ma);
        float s1 = hsum(sb), m1 = hmax(mb);

        // wave-64 butterfly; the two channels' chains interleave (ILP)
        #pragma unroll
        for (int m = 32; m >= 1; m >>= 1) {
            s0 += __shfl_xor(s0, m, 64);
            s1 += __shfl_xor(s1, m, 64);
            m0 = fmaxf(m0, __shfl_xor(m0, m, 64));
            m1 = fmaxf(m1, __shfl_xor(m1, m, 64));
        }
        if (lane == 0) {
            s_mean[c0]     = s0 * (1.0f / 1024.0f);
            s_mean[c0 + 1] = s1 * (1.0f / 1024.0f);
            s_max[c0]      = m0;
            s_max[c0 + 1]  = m1;
        }
    }
    __syncthreads();

    // ---- Phase 2: grouped 64->64->64 MLP; wave0=mean path, wave1=max path ----
    float acc2 = 0.f;
    if (wave < 2) {
        const float* src = wave ? s_max : s_mean;
        const float* w1o = w1 + ((size_t)o * Cc + lane) * Cc;
        float a = 0.f;
        #pragma unroll
        for (int c2 = 0; c2 < Cc; ++c2) a = fmaf(src[c2], w1o[c2], a);
        (wave ? s_hx : s_hm)[lane] = fmaxf(a, 0.f);
    }
    __syncthreads();

    if (wave < 2) {
        const float* src = wave ? s_hx : s_hm;
        const float* w2o = w2 + ((size_t)o * Cc + lane) * Cc;
        #pragma unroll
        for (int h = 0; h < Cc; ++h) acc2 = fmaf(src[h], w2o[h], acc2);
        if (wave == 1) s_ax[lane] = acc2;
    }
    __syncthreads();

    if (wave == 0) {
        const float z = acc2 + s_ax[lane];
        out[(size_t)blk * Cc + lane] = 1.0f / (1.0f + __expf(-z));
    }
}

extern "C" void kernel_launch(void* const* d_in, const int* in_sizes, int n_in,
                              void* d_out, int out_size, void* d_ws, size_t ws_size,
                              hipStream_t stream) {
    const float* x  = (const float*)d_in[0];
    const float* w1 = (const float*)d_in[1];
    const float* w2 = (const float*)d_in[2];
    float* out = (float*)d_out;

    ca_fused<<<NBLK, 256, 0, stream>>>(x, w1, w2, out);
}